// Round 4
// baseline (678.820 us; speedup 1.0000x reference)
//
#include <hip/hip_runtime.h>

// ---------------------------------------------------------------------------
// Sparse MS-Deformable Attention, f32.
// Round 4:
//  (a) sampler QPB 4->2: LDS 39.4->19.5 KB -> 8 blocks/CU (occupancy cap
//      50%->100%), keeping VGPR=64 (8 waves/SIMD). Latency-bound gather
//      needs TLP, which LDS was capping.
//  (b) GEMMs register-blocked 8q x 4c: 4x less LDS read traffic (was
//      LDS-BW-bound at ~55 us each), now ~VALU-bound.
// ---------------------------------------------------------------------------

typedef float f32x4 __attribute__((ext_vector_type(4)));

// Y[n, 0:M] = X[n, 0:256] @ W[256, M] + bias ; 32 rows/block, M threads,
// thread tile = 8 queries x 4 cols. Safe in-place (Y==X): block stages its
// 32 rows to LDS before any write.
template<int M>
__global__ __launch_bounds__(M)
void gemm_rb(const float* __restrict__ X, const float* __restrict__ W,
             const float* __restrict__ bias, float* __restrict__ Y) {
    __shared__ float xt[32 * 256];
    const int tid = threadIdx.x;
    const long row0 = (long)blockIdx.x * 32;
    const float4* src = (const float4*)(X + row0 * 256);
    float4* dst4 = (float4*)xt;
    for (int i = tid; i < 32 * 64; i += M) dst4[i] = src[i];
    __syncthreads();

    constexpr int CG = M / 4;
    const int cg = tid % CG, qg = tid / CG;    // qg in 0..3
    const int c0 = cg * 4, q0 = qg * 8;

    f32x4 acc[8];
#pragma unroll
    for (int qi = 0; qi < 8; ++qi) acc[qi] = (f32x4){0.f, 0.f, 0.f, 0.f};

    for (int k4 = 0; k4 < 64; ++k4) {
        f32x4 w[4];
#pragma unroll
        for (int r = 0; r < 4; ++r)
            w[r] = *(const f32x4*)&W[(size_t)(k4 * 4 + r) * M + c0];
        f32x4 xv[8];
#pragma unroll
        for (int qi = 0; qi < 8; ++qi)
            xv[qi] = *(const f32x4*)&xt[(q0 + qi) * 256 + k4 * 4];
#pragma unroll
        for (int qi = 0; qi < 8; ++qi) {
            f32x4 a = acc[qi];
            const f32x4 x = xv[qi];
            a.x = fmaf(x.x, w[0].x, a.x); a.y = fmaf(x.x, w[0].y, a.y);
            a.z = fmaf(x.x, w[0].z, a.z); a.w = fmaf(x.x, w[0].w, a.w);
            a.x = fmaf(x.y, w[1].x, a.x); a.y = fmaf(x.y, w[1].y, a.y);
            a.z = fmaf(x.y, w[1].z, a.z); a.w = fmaf(x.y, w[1].w, a.w);
            a.x = fmaf(x.z, w[2].x, a.x); a.y = fmaf(x.z, w[2].y, a.y);
            a.z = fmaf(x.z, w[2].z, a.z); a.w = fmaf(x.z, w[2].w, a.w);
            a.x = fmaf(x.w, w[3].x, a.x); a.y = fmaf(x.w, w[3].y, a.y);
            a.z = fmaf(x.w, w[3].z, a.z); a.w = fmaf(x.w, w[3].w, a.w);
            acc[qi] = a;
        }
    }

    const f32x4 bv = *(const f32x4*)&bias[c0];
#pragma unroll
    for (int qi = 0; qi < 8; ++qi) {
        f32x4 o = acc[qi];
        o.x += bv.x; o.y += bv.y; o.z += bv.z; o.w += bv.w;
        *(f32x4*)&Y[(size_t)(row0 + q0 + qi) * M + c0] = o;
    }
}

// 2 queries per block. 256 threads = 8 heads x 32 lanes; lane owns 8 raw
// channels. Softmax(logits) in LDS, bilerp raw v rows with pinned-MLP corner
// loads, attn-weighted accumulate -> sAgg, fused W_val projection.
#define QPB 2
__global__ __launch_bounds__(256, 8)
void sample_agg_proj(const float* __restrict__ offs_all,
                     const float* __restrict__ logits_all,
                     const float* __restrict__ refpts,
                     const int* __restrict__ qoff, int n_off,
                     const float* __restrict__ v0, const float* __restrict__ v1,
                     const float* __restrict__ v2, const float* __restrict__ v3,
                     const float* __restrict__ W_val, const float* __restrict__ b_val,
                     float* __restrict__ val_out) {
    __shared__ float sOff[QPB][256];
    __shared__ float sAttn[QPB][128];
    __shared__ float sRef[QPB][2];
    __shared__ float sAgg[QPB][8][256];
    const int n0 = blockIdx.x * QPB;
    const int tid = threadIdx.x;

    if (tid < QPB * 64) ((f32x4*)sOff)[tid] = ((const f32x4*)(offs_all + (size_t)n0 * 256))[tid];
    else if (tid < QPB * 64 + QPB * 32)
        ((f32x4*)sAttn)[tid - QPB * 64] = ((const f32x4*)(logits_all + (size_t)n0 * 128))[tid - QPB * 64];
    if (tid >= 192 && tid < 192 + QPB * 2) ((float*)sRef)[tid - 192] = refpts[(size_t)n0 * 2 + (tid - 192)];
    __syncthreads();

    // softmax over 16 for each of QPB*8 (q,h) rows
    if (tid < QPB * 8) {
        float* row = &sAttn[tid >> 3][(tid & 7) * 16];
        float m = -1e30f;
#pragma unroll
        for (int i = 0; i < 16; ++i) m = fmaxf(m, row[i]);
        float s = 0.f;
#pragma unroll
        for (int i = 0; i < 16; ++i) { const float e = expf(row[i] - m); row[i] = e; s += e; }
        const float inv = 1.f / s;
#pragma unroll
        for (int i = 0; i < 16; ++i) row[i] *= inv;
    }
    __syncthreads();

    const int h = tid >> 5, g = tid & 31;
    const float* vptr[4] = {v0, v1, v2, v3};
    const int dims[4] = {64, 128, 256, 512};

    for (int q = 0; q < QPB; ++q) {
        const int n = n0 + q;
        int b = 0;
        for (int i = 1; i < n_off; ++i) if (n >= qoff[i]) b = i;
        const float ri = sRef[q][0];
        const float rj = sRef[q][1];

        float acc[8];
#pragma unroll
        for (int j = 0; j < 8; ++j) acc[j] = 0.f;

#pragma unroll
        for (int l = 0; l < 4; ++l) {
            const int hw = dims[l];
            const float sc = (float)hw * (1.0f / 512.0f);
            const float* __restrict__ vb = vptr[l] + (size_t)b * hw * hw * 256 + g * 8;

            int   coff[4][4];
            float wgt[4][4];
#pragma unroll
            for (int p = 0; p < 4; ++p) {
                const int oi = ((h * 4 + l) * 4 + p) * 2;
                const float fi = (ri + sOff[q][oi]) * sc;
                const float fj = (rj + sOff[q][oi + 1]) * sc;
                const float a = sAttn[q][(h * 4 + l) * 4 + p];
                const float sci = fmaxf(fi - 0.5f, 0.f);
                const float scj = fmaxf(fj - 0.5f, 0.f);
                const float fl_i = floorf(sci), fl_j = floorf(scj);
                const int i0 = (int)fl_i, j0 = (int)fl_j;
                const float fri = sci - fl_i, frj = scj - fl_j;
                const int i0c = min(i0, hw - 1), i1c = min(i0 + 1, hw - 1);
                const int j0c = min(j0, hw - 1), j1c = min(j0 + 1, hw - 1);
                coff[p][0] = (i0c * hw + j0c) * 256;
                coff[p][1] = (i0c * hw + j1c) * 256;
                coff[p][2] = (i1c * hw + j0c) * 256;
                coff[p][3] = (i1c * hw + j1c) * 256;
                const float uw = 1.f - fri, lw = 1.f - frj;
                wgt[p][0] = uw * lw * a;
                wgt[p][1] = uw * frj * a;
                wgt[p][2] = fri * lw * a;
                wgt[p][3] = fri * frj * a;
            }

#pragma unroll
            for (int p = 0; p < 4; ++p) {
                f32x4 buf[8];
                const f32x4* c0 = (const f32x4*)(vb + (size_t)coff[p][0]);
                const f32x4* c1 = (const f32x4*)(vb + (size_t)coff[p][1]);
                const f32x4* c2p = (const f32x4*)(vb + (size_t)coff[p][2]);
                const f32x4* c3 = (const f32x4*)(vb + (size_t)coff[p][3]);
                buf[0] = c0[0]; buf[1] = c0[1];
                buf[2] = c1[0]; buf[3] = c1[1];
                buf[4] = c2p[0]; buf[5] = c2p[1];
                buf[6] = c3[0]; buf[7] = c3[1];
                // Pin all 8 loads in flight: scheduler cannot sink them.
                asm volatile("" : "+v"(buf[0]), "+v"(buf[1]), "+v"(buf[2]), "+v"(buf[3]),
                                  "+v"(buf[4]), "+v"(buf[5]), "+v"(buf[6]), "+v"(buf[7]));
#pragma unroll
                for (int cr = 0; cr < 4; ++cr) {
                    const float wv = wgt[p][cr];
                    const f32x4 u  = buf[cr * 2 + 0];
                    const f32x4 w4 = buf[cr * 2 + 1];
                    acc[0] = fmaf(wv, u.x,  acc[0]);
                    acc[1] = fmaf(wv, u.y,  acc[1]);
                    acc[2] = fmaf(wv, u.z,  acc[2]);
                    acc[3] = fmaf(wv, u.w,  acc[3]);
                    acc[4] = fmaf(wv, w4.x, acc[4]);
                    acc[5] = fmaf(wv, w4.y, acc[5]);
                    acc[6] = fmaf(wv, w4.z, acc[6]);
                    acc[7] = fmaf(wv, w4.w, acc[7]);
                }
            }
        }

        f32x4* sa4 = (f32x4*)(&sAgg[q][h][g * 8]);
        sa4[0] = (f32x4){acc[0], acc[1], acc[2], acc[3]};
        sa4[1] = (f32x4){acc[4], acc[5], acc[6], acc[7]};
    }
    __syncthreads();

    // projection: out channel c2 = tid, head h2 = c2/32; W_val row loads
    // shared across the QPB queries.
    const int c2 = tid, h2 = tid >> 5;
    float s[QPB];
#pragma unroll
    for (int q = 0; q < QPB; ++q) s[q] = b_val[c2];
    for (int k4 = 0; k4 < 64; ++k4) {
        const float w0 = W_val[(k4 * 4 + 0) * 256 + c2];
        const float w1 = W_val[(k4 * 4 + 1) * 256 + c2];
        const float w2 = W_val[(k4 * 4 + 2) * 256 + c2];
        const float w3 = W_val[(k4 * 4 + 3) * 256 + c2];
#pragma unroll
        for (int q = 0; q < QPB; ++q) {
            const f32x4 av = ((const f32x4*)sAgg[q][h2])[k4];
            float t = s[q];
            t = fmaf(av.x, w0, t);
            t = fmaf(av.y, w1, t);
            t = fmaf(av.z, w2, t);
            t = fmaf(av.w, w3, t);
            s[q] = t;
        }
    }
#pragma unroll
    for (int q = 0; q < QPB; ++q)
        val_out[(size_t)(n0 + q) * 256 + c2] = s[q];
}

extern "C" void kernel_launch(void* const* d_in, const int* in_sizes, int n_in,
                              void* d_out, int out_size, void* d_ws, size_t ws_size,
                              hipStream_t stream) {
    const float* query  = (const float*)d_in[0];
    const int*   qoff   = (const int*)d_in[1];
    const float* refp   = (const float*)d_in[2];
    const float* v0     = (const float*)d_in[3];
    const float* v1     = (const float*)d_in[4];
    const float* v2     = (const float*)d_in[5];
    const float* v3     = (const float*)d_in[6];
    const float* W_off  = (const float*)d_in[7];
    const float* b_off  = (const float*)d_in[8];
    const float* W_attn = (const float*)d_in[9];
    const float* b_attn = (const float*)d_in[10];
    const float* W_val  = (const float*)d_in[11];
    const float* b_val  = (const float*)d_in[12];
    const float* W_out  = (const float*)d_in[13];
    const float* b_out  = (const float*)d_in[14];
    float* out = (float*)d_out;

    const int N = in_sizes[0] / 256;   // 16384
    const int n_off = in_sizes[1];     // 2

    float* P1off  = (float*)d_ws;                 // N*256 f32 (offsets)
    float* P1attn = P1off + (size_t)N * 256;      // N*128 f32 (attn logits)

    gemm_rb<256><<<N / 32, 256, 0, stream>>>(query, W_off, b_off, P1off);
    gemm_rb<128><<<N / 32, 128, 0, stream>>>(query, W_attn, b_attn, P1attn);
    // softmax fused into sample_agg_proj (reads logits).
    sample_agg_proj<<<N / QPB, 256, 0, stream>>>(P1off, P1attn, refp, qoff, n_off,
                                                 v0, v1, v2, v3, W_val, b_val, out);
    gemm_rb<256><<<N / 32, 256, 0, stream>>>(out, W_out, b_out, out);
}

// Round 5
// 587.448 us; speedup vs baseline: 1.1555x; 1.1555x over previous
//
#include <hip/hip_runtime.h>

// ---------------------------------------------------------------------------
// Sparse MS-Deformable Attention, f32.
// Round 5: QPB=2 (LDS 19.5 KB -> 8 blocks/CU) with __launch_bounds__(256,4).
// Round 4's (256,8) hard-capped VGPR at 64 and triggered a spill cascade
// (VGPR=32, WRITE_SIZE 188 MB scratch). With the (256,4) bound the allocator
// lands on exactly 64 VGPR spill-free (observed round 3), which itself
// permits 8 waves/SIMD -> occupancy becomes LDS-capped at 8 blocks/CU.
// GEMMs keep the round-4 register-blocked 8x4 tile (182 -> 85 us, kept).
// ---------------------------------------------------------------------------

typedef float f32x4 __attribute__((ext_vector_type(4)));

// Y[n, 0:M] = X[n, 0:256] @ W[256, M] + bias ; 32 rows/block, M threads,
// thread tile = 8 queries x 4 cols. Safe in-place (Y==X): block stages its
// 32 rows to LDS before any write.
template<int M>
__global__ __launch_bounds__(M)
void gemm_rb(const float* __restrict__ X, const float* __restrict__ W,
             const float* __restrict__ bias, float* __restrict__ Y) {
    __shared__ float xt[32 * 256];
    const int tid = threadIdx.x;
    const long row0 = (long)blockIdx.x * 32;
    const float4* src = (const float4*)(X + row0 * 256);
    float4* dst4 = (float4*)xt;
    for (int i = tid; i < 32 * 64; i += M) dst4[i] = src[i];
    __syncthreads();

    constexpr int CG = M / 4;
    const int cg = tid % CG, qg = tid / CG;    // qg in 0..3
    const int c0 = cg * 4, q0 = qg * 8;

    f32x4 acc[8];
#pragma unroll
    for (int qi = 0; qi < 8; ++qi) acc[qi] = (f32x4){0.f, 0.f, 0.f, 0.f};

    for (int k4 = 0; k4 < 64; ++k4) {
        f32x4 w[4];
#pragma unroll
        for (int r = 0; r < 4; ++r)
            w[r] = *(const f32x4*)&W[(size_t)(k4 * 4 + r) * M + c0];
        f32x4 xv[8];
#pragma unroll
        for (int qi = 0; qi < 8; ++qi)
            xv[qi] = *(const f32x4*)&xt[(q0 + qi) * 256 + k4 * 4];
#pragma unroll
        for (int qi = 0; qi < 8; ++qi) {
            f32x4 a = acc[qi];
            const f32x4 x = xv[qi];
            a.x = fmaf(x.x, w[0].x, a.x); a.y = fmaf(x.x, w[0].y, a.y);
            a.z = fmaf(x.x, w[0].z, a.z); a.w = fmaf(x.x, w[0].w, a.w);
            a.x = fmaf(x.y, w[1].x, a.x); a.y = fmaf(x.y, w[1].y, a.y);
            a.z = fmaf(x.y, w[1].z, a.z); a.w = fmaf(x.y, w[1].w, a.w);
            a.x = fmaf(x.z, w[2].x, a.x); a.y = fmaf(x.z, w[2].y, a.y);
            a.z = fmaf(x.z, w[2].z, a.z); a.w = fmaf(x.z, w[2].w, a.w);
            a.x = fmaf(x.w, w[3].x, a.x); a.y = fmaf(x.w, w[3].y, a.y);
            a.z = fmaf(x.w, w[3].z, a.z); a.w = fmaf(x.w, w[3].w, a.w);
            acc[qi] = a;
        }
    }

    const f32x4 bv = *(const f32x4*)&bias[c0];
#pragma unroll
    for (int qi = 0; qi < 8; ++qi) {
        f32x4 o = acc[qi];
        o.x += bv.x; o.y += bv.y; o.z += bv.z; o.w += bv.w;
        *(f32x4*)&Y[(size_t)(row0 + q0 + qi) * M + c0] = o;
    }
}

// 2 queries per block. 256 threads = 8 heads x 32 lanes; lane owns 8 raw
// channels. Softmax(logits) in LDS, bilerp raw v rows with pinned-MLP corner
// loads, attn-weighted accumulate -> sAgg, fused W_val projection.
#define QPB 2
__global__ __launch_bounds__(256, 4)
void sample_agg_proj(const float* __restrict__ offs_all,
                     const float* __restrict__ logits_all,
                     const float* __restrict__ refpts,
                     const int* __restrict__ qoff, int n_off,
                     const float* __restrict__ v0, const float* __restrict__ v1,
                     const float* __restrict__ v2, const float* __restrict__ v3,
                     const float* __restrict__ W_val, const float* __restrict__ b_val,
                     float* __restrict__ val_out) {
    __shared__ float sOff[QPB][256];
    __shared__ float sAttn[QPB][128];
    __shared__ float sRef[QPB][2];
    __shared__ float sAgg[QPB][8][256];
    const int n0 = blockIdx.x * QPB;
    const int tid = threadIdx.x;

    if (tid < QPB * 64) ((f32x4*)sOff)[tid] = ((const f32x4*)(offs_all + (size_t)n0 * 256))[tid];
    else if (tid < QPB * 64 + QPB * 32)
        ((f32x4*)sAttn)[tid - QPB * 64] = ((const f32x4*)(logits_all + (size_t)n0 * 128))[tid - QPB * 64];
    if (tid >= 192 && tid < 192 + QPB * 2) ((float*)sRef)[tid - 192] = refpts[(size_t)n0 * 2 + (tid - 192)];
    __syncthreads();

    // softmax over 16 for each of QPB*8 (q,h) rows
    if (tid < QPB * 8) {
        float* row = &sAttn[tid >> 3][(tid & 7) * 16];
        float m = -1e30f;
#pragma unroll
        for (int i = 0; i < 16; ++i) m = fmaxf(m, row[i]);
        float s = 0.f;
#pragma unroll
        for (int i = 0; i < 16; ++i) { const float e = expf(row[i] - m); row[i] = e; s += e; }
        const float inv = 1.f / s;
#pragma unroll
        for (int i = 0; i < 16; ++i) row[i] *= inv;
    }
    __syncthreads();

    const int h = tid >> 5, g = tid & 31;
    const float* vptr[4] = {v0, v1, v2, v3};
    const int dims[4] = {64, 128, 256, 512};

    for (int q = 0; q < QPB; ++q) {
        const int n = n0 + q;
        int b = 0;
        for (int i = 1; i < n_off; ++i) if (n >= qoff[i]) b = i;
        const float ri = sRef[q][0];
        const float rj = sRef[q][1];

        float acc[8];
#pragma unroll
        for (int j = 0; j < 8; ++j) acc[j] = 0.f;

#pragma unroll
        for (int l = 0; l < 4; ++l) {
            const int hw = dims[l];
            const float sc = (float)hw * (1.0f / 512.0f);
            const float* __restrict__ vb = vptr[l] + (size_t)b * hw * hw * 256 + g * 8;

            int   coff[4][4];
            float wgt[4][4];
#pragma unroll
            for (int p = 0; p < 4; ++p) {
                const int oi = ((h * 4 + l) * 4 + p) * 2;
                const float fi = (ri + sOff[q][oi]) * sc;
                const float fj = (rj + sOff[q][oi + 1]) * sc;
                const float a = sAttn[q][(h * 4 + l) * 4 + p];
                const float sci = fmaxf(fi - 0.5f, 0.f);
                const float scj = fmaxf(fj - 0.5f, 0.f);
                const float fl_i = floorf(sci), fl_j = floorf(scj);
                const int i0 = (int)fl_i, j0 = (int)fl_j;
                const float fri = sci - fl_i, frj = scj - fl_j;
                const int i0c = min(i0, hw - 1), i1c = min(i0 + 1, hw - 1);
                const int j0c = min(j0, hw - 1), j1c = min(j0 + 1, hw - 1);
                coff[p][0] = (i0c * hw + j0c) * 256;
                coff[p][1] = (i0c * hw + j1c) * 256;
                coff[p][2] = (i1c * hw + j0c) * 256;
                coff[p][3] = (i1c * hw + j1c) * 256;
                const float uw = 1.f - fri, lw = 1.f - frj;
                wgt[p][0] = uw * lw * a;
                wgt[p][1] = uw * frj * a;
                wgt[p][2] = fri * lw * a;
                wgt[p][3] = fri * frj * a;
            }

#pragma unroll
            for (int p = 0; p < 4; ++p) {
                f32x4 buf[8];
                const f32x4* c0 = (const f32x4*)(vb + (size_t)coff[p][0]);
                const f32x4* c1 = (const f32x4*)(vb + (size_t)coff[p][1]);
                const f32x4* c2p = (const f32x4*)(vb + (size_t)coff[p][2]);
                const f32x4* c3 = (const f32x4*)(vb + (size_t)coff[p][3]);
                buf[0] = c0[0]; buf[1] = c0[1];
                buf[2] = c1[0]; buf[3] = c1[1];
                buf[4] = c2p[0]; buf[5] = c2p[1];
                buf[6] = c3[0]; buf[7] = c3[1];
                // Pin all 8 loads in flight: scheduler cannot sink them.
                asm volatile("" : "+v"(buf[0]), "+v"(buf[1]), "+v"(buf[2]), "+v"(buf[3]),
                                  "+v"(buf[4]), "+v"(buf[5]), "+v"(buf[6]), "+v"(buf[7]));
#pragma unroll
                for (int cr = 0; cr < 4; ++cr) {
                    const float wv = wgt[p][cr];
                    const f32x4 u  = buf[cr * 2 + 0];
                    const f32x4 w4 = buf[cr * 2 + 1];
                    acc[0] = fmaf(wv, u.x,  acc[0]);
                    acc[1] = fmaf(wv, u.y,  acc[1]);
                    acc[2] = fmaf(wv, u.z,  acc[2]);
                    acc[3] = fmaf(wv, u.w,  acc[3]);
                    acc[4] = fmaf(wv, w4.x, acc[4]);
                    acc[5] = fmaf(wv, w4.y, acc[5]);
                    acc[6] = fmaf(wv, w4.z, acc[6]);
                    acc[7] = fmaf(wv, w4.w, acc[7]);
                }
            }
        }

        f32x4* sa4 = (f32x4*)(&sAgg[q][h][g * 8]);
        sa4[0] = (f32x4){acc[0], acc[1], acc[2], acc[3]};
        sa4[1] = (f32x4){acc[4], acc[5], acc[6], acc[7]};
    }
    __syncthreads();

    // projection: out channel c2 = tid, head h2 = c2/32; W_val row loads
    // shared across the QPB queries.
    const int c2 = tid, h2 = tid >> 5;
    float s[QPB];
#pragma unroll
    for (int q = 0; q < QPB; ++q) s[q] = b_val[c2];
    for (int k4 = 0; k4 < 64; ++k4) {
        const float w0 = W_val[(k4 * 4 + 0) * 256 + c2];
        const float w1 = W_val[(k4 * 4 + 1) * 256 + c2];
        const float w2 = W_val[(k4 * 4 + 2) * 256 + c2];
        const float w3 = W_val[(k4 * 4 + 3) * 256 + c2];
#pragma unroll
        for (int q = 0; q < QPB; ++q) {
            const f32x4 av = ((const f32x4*)sAgg[q][h2])[k4];
            float t = s[q];
            t = fmaf(av.x, w0, t);
            t = fmaf(av.y, w1, t);
            t = fmaf(av.z, w2, t);
            t = fmaf(av.w, w3, t);
            s[q] = t;
        }
    }
#pragma unroll
    for (int q = 0; q < QPB; ++q)
        val_out[(size_t)(n0 + q) * 256 + c2] = s[q];
}

extern "C" void kernel_launch(void* const* d_in, const int* in_sizes, int n_in,
                              void* d_out, int out_size, void* d_ws, size_t ws_size,
                              hipStream_t stream) {
    const float* query  = (const float*)d_in[0];
    const int*   qoff   = (const int*)d_in[1];
    const float* refp   = (const float*)d_in[2];
    const float* v0     = (const float*)d_in[3];
    const float* v1     = (const float*)d_in[4];
    const float* v2     = (const float*)d_in[5];
    const float* v3     = (const float*)d_in[6];
    const float* W_off  = (const float*)d_in[7];
    const float* b_off  = (const float*)d_in[8];
    const float* W_attn = (const float*)d_in[9];
    const float* b_attn = (const float*)d_in[10];
    const float* W_val  = (const float*)d_in[11];
    const float* b_val  = (const float*)d_in[12];
    const float* W_out  = (const float*)d_in[13];
    const float* b_out  = (const float*)d_in[14];
    float* out = (float*)d_out;

    const int N = in_sizes[0] / 256;   // 16384
    const int n_off = in_sizes[1];     // 2

    float* P1off  = (float*)d_ws;                 // N*256 f32 (offsets)
    float* P1attn = P1off + (size_t)N * 256;      // N*128 f32 (attn logits)

    gemm_rb<256><<<N / 32, 256, 0, stream>>>(query, W_off, b_off, P1off);
    gemm_rb<128><<<N / 32, 128, 0, stream>>>(query, W_attn, b_attn, P1attn);
    // softmax fused into sample_agg_proj (reads logits).
    sample_agg_proj<<<N / QPB, 256, 0, stream>>>(P1off, P1attn, refp, qoff, n_off,
                                                 v0, v1, v2, v3, W_val, b_val, out);
    gemm_rb<256><<<N / 32, 256, 0, stream>>>(out, W_out, b_out, out);
}